// Round 1
// baseline (478.676 us; speedup 1.0000x reference)
//
#include <hip/hip_runtime.h>
#include <hip/hip_bf16.h>

// Problem constants (from reference): N=20000 nodes, E=200000 edges, H=8, C=256,
// IN=256, OUT=250, H*C=2048.

typedef __attribute__((ext_vector_type(8))) short short8v;
typedef __attribute__((ext_vector_type(4))) float float4v;

__device__ __forceinline__ unsigned f2bfu(float f) {
  unsigned u = __float_as_uint(f);
  return (u + 0x7fffu + ((u >> 16) & 1u)) >> 16;  // RNE f32 -> bf16
}
__device__ __forceinline__ float bfu_lo(unsigned u) { return __uint_as_float(u << 16); }
__device__ __forceinline__ float bfu_hi(unsigned u) { return __uint_as_float(u & 0xffff0000u); }
__device__ __forceinline__ unsigned pack2(float a, float b) { return f2bfu(a) | (f2bfu(b) << 16); }

__device__ __forceinline__ void gll16(const void* g, void* l) {
  // async global->LDS, 16B per lane; LDS dest = wave-uniform base + lane*16
  __builtin_amdgcn_global_load_lds(
      (__attribute__((address_space(1))) void*)const_cast<void*>(g),
      (__attribute__((address_space(3))) void*)(l), 16, 0, 0);
}

// ---------------- small prep kernels ----------------

// f32 -> bf16, 8 elems/thread
__global__ void cvt_kernel(const float* __restrict__ in, short* __restrict__ out, int n8) {
  int g = blockIdx.x * 256 + threadIdx.x;
  if (g >= n8) return;
  const float4* p = (const float4*)in + (size_t)g * 2;
  float4 a = p[0], b = p[1];
  int4 o;
  o.x = (int)pack2(a.x, a.y);
  o.y = (int)pack2(a.z, a.w);
  o.z = (int)pack2(b.x, b.y);
  o.w = (int)pack2(b.z, b.w);
  ((int4*)out)[g] = o;
}

// out[c][r] = bf16(in[r][c]); zero-pads columns c in [Cc, Cpad)
__global__ void transpose_kernel(const float* __restrict__ in, short* __restrict__ out,
                                 int R, int Cc, int Cpad) {
  __shared__ float tile[32][33];
  int tx = threadIdx.x, ty = threadIdx.y;
  int c0 = blockIdx.x * 32, r0 = blockIdx.y * 32;
  #pragma unroll
  for (int j = ty; j < 32; j += 8) {
    int r = r0 + j, c = c0 + tx;
    tile[j][tx] = (r < R && c < Cc) ? in[(size_t)r * Cc + c] : 0.f;
  }
  __syncthreads();
  #pragma unroll
  for (int j = ty; j < 32; j += 8) {
    int c = c0 + j, r = r0 + tx;
    if (c < Cpad && r < R) out[(size_t)c * R + r] = (short)f2bfu(tile[tx][j]);
  }
}

// ws_s[k*8+h] = sum_c W_gat[k][h*256+c]*att_src[h][c]   (collapses att dot into x-space)
__global__ void prepws_kernel(const float* __restrict__ W, const float* __restrict__ att_s,
                              const float* __restrict__ att_d, float* __restrict__ ws_s,
                              float* __restrict__ ws_d) {
  int g = blockIdx.x * 256 + threadIdx.x;  // 0..2047
  int k = g >> 3, h = g & 7;
  const float* wr = W + (size_t)k * 2048 + h * 256;
  const float* as = att_s + h * 256;
  const float* ad = att_d + h * 256;
  float s = 0.f, dd = 0.f;
  for (int c = 0; c < 256; ++c) {
    float wv = wr[c];
    s += wv * as[c];
    dd += wv * ad[c];
  }
  ws_s[g] = s;
  ws_d[g] = dd;
}

// a_s[n][h] = x[n,:] . ws_s[:,h]  (f32 exact path for attention logits)
__global__ __launch_bounds__(256) void asd_kernel(const float* __restrict__ x,
    const float* __restrict__ ws_s, const float* __restrict__ ws_d,
    float* __restrict__ a_s, float* __restrict__ a_d) {
  __shared__ float ls[2048], ld2[2048];
  int tid = threadIdx.x;
  for (int i = tid; i < 2048; i += 256) { ls[i] = ws_s[i]; ld2[i] = ws_d[i]; }
  __syncthreads();
  int node = blockIdx.x * 32 + (tid >> 3);
  int h = tid & 7;
  const float4* xr = (const float4*)(x + (size_t)node * 256);
  float as = 0.f, ad = 0.f;
  for (int k4 = 0; k4 < 64; ++k4) {
    float4 v = xr[k4];
    int k8 = k4 * 32 + h;
    as += v.x * ls[k8] + v.y * ls[k8 + 8] + v.z * ls[k8 + 16] + v.w * ls[k8 + 24];
    ad += v.x * ld2[k8] + v.y * ld2[k8 + 8] + v.z * ld2[k8 + 16] + v.w * ld2[k8 + 24];
  }
  a_s[node * 8 + h] = as;
  a_d[node * 8 + h] = ad;
}

// ---------------- bf16 MFMA GEMM (m97-style 128x128 tile, BK=32) ----------------
// C[M][N] = A[M][K] * BT[N][K]^T ; EPI=0: bf16 store, EPI=1: f32 store + bias, col<Nout
template <int EPI>
__global__ __launch_bounds__(256, 2) void gemm_kernel(
    const short* __restrict__ A, const short* __restrict__ BT,
    int M, int Npad, int K,
    short* __restrict__ Cb, float* __restrict__ Cf,
    const float* __restrict__ bias, int Nout) {
  __shared__ short lA[128 * 32];
  __shared__ short lB[128 * 32];
  int tid = threadIdx.x;
  int wave = tid >> 6, lane = tid & 63;
  int nt = Npad >> 7;
  int m0 = (blockIdx.x / nt) << 7;
  int n0 = (blockIdx.x % nt) << 7;
  int wm = wave >> 1, wn = wave & 1;

  float4v acc[4][4];
  #pragma unroll
  for (int i = 0; i < 4; ++i)
    #pragma unroll
    for (int j = 0; j < 4; ++j) acc[i][j] = (float4v){0.f, 0.f, 0.f, 0.f};

  int l4 = lane >> 2;          // row within 16-row staging chunk
  int lk = (lane & 3) << 3;    // k element offset within chunk row
  int lr = lane & 15, lq = lane >> 4;

  for (int k0 = 0; k0 < K; k0 += 32) {
    __syncthreads();
    #pragma unroll
    for (int i = 0; i < 2; ++i) {
      int c = wave * 2 + i;
      int ar = m0 + c * 16 + l4;
      if (ar >= M) ar = M - 1;  // clamp; masked at store
      gll16(A + (size_t)ar * K + k0 + lk, lA + c * 512);
      int br = n0 + c * 16 + l4;
      gll16(BT + (size_t)br * K + k0 + lk, lB + c * 512);
    }
    __syncthreads();
    short8v af[4], bfv[4];
    #pragma unroll
    for (int i = 0; i < 4; ++i)
      af[i] = *(const short8v*)(lA + (wm * 64 + i * 16 + lr) * 32 + lq * 8);
    #pragma unroll
    for (int j = 0; j < 4; ++j)
      bfv[j] = *(const short8v*)(lB + (wn * 64 + j * 16 + lr) * 32 + lq * 8);
    #pragma unroll
    for (int i = 0; i < 4; ++i)
      #pragma unroll
      for (int j = 0; j < 4; ++j)
        acc[i][j] = __builtin_amdgcn_mfma_f32_16x16x32_bf16(af[i], bfv[j], acc[i][j], 0, 0, 0);
  }

  #pragma unroll
  for (int i = 0; i < 4; ++i) {
    #pragma unroll
    for (int jj = 0; jj < 4; ++jj) {
      int row = m0 + wm * 64 + i * 16 + lq * 4 + jj;  // C/D: row=(l>>4)*4+reg, col=l&15
      if (row >= M) continue;
      #pragma unroll
      for (int j = 0; j < 4; ++j) {
        int col = n0 + wn * 64 + j * 16 + lr;
        float v = acc[i][j][jj];
        if (EPI == 0) {
          Cb[(size_t)row * Npad + col] = (short)f2bfu(v);
        } else {
          if (col < Nout) Cf[(size_t)row * Nout + col] = v + bias[col];
        }
      }
    }
  }
}

// ---------------- CSR build ----------------

__global__ void hist_kernel(const int* __restrict__ ei, int* __restrict__ deg, int E) {
  int e = blockIdx.x * 256 + threadIdx.x;
  if (e < E) atomicAdd(&deg[ei[E + e]], 1);
}

__global__ __launch_bounds__(1024) void scan_kernel(const int* __restrict__ deg,
                                                    int* __restrict__ rowptr,
                                                    int* __restrict__ cursor, int n) {
  __shared__ int s[1024];
  __shared__ int s_run;
  int t = threadIdx.x;
  if (t == 0) { s_run = 0; rowptr[0] = 0; }
  __syncthreads();
  for (int base = 0; base < n; base += 1024) {
    int idx = base + t;
    int v = (idx < n) ? deg[idx] : 0;
    s[t] = v;
    __syncthreads();
    for (int off = 1; off < 1024; off <<= 1) {
      int add = (t >= off) ? s[t - off] : 0;
      __syncthreads();
      s[t] += add;
      __syncthreads();
    }
    int incl = s[t];
    int run0 = s_run;
    __syncthreads();
    if (idx < n) {
      rowptr[idx + 1] = run0 + incl;
      cursor[idx] = run0 + incl - v;  // exclusive prefix
    }
    if (t == 1023) s_run = run0 + s[1023];
    __syncthreads();
  }
}

__global__ void scatter_kernel(const int* __restrict__ ei, int* __restrict__ cursor,
                               int* __restrict__ csr_src, int E) {
  int e = blockIdx.x * 256 + threadIdx.x;
  if (e < E) {
    int pos = atomicAdd(&cursor[ei[E + e]], 1);
    csr_src[pos] = ei[e];
  }
}

// ---------------- per-dst softmax + aggregate ----------------
#define MAXE 512
__global__ __launch_bounds__(256) void agg_kernel(
    const short* __restrict__ xh, const float* __restrict__ a_s,
    const float* __restrict__ a_d, const int* __restrict__ rowptr,
    const int* __restrict__ csr_src, const float* __restrict__ b_gat,
    short* __restrict__ agg, float* __restrict__ pooled) {
  __shared__ int s_src[MAXE];
  __shared__ float s_p[MAXE * 8];
  __shared__ float s_ad[8];
  __shared__ float s_inv[8];
  __shared__ float s_red[256];
  int d = blockIdx.x, tid = threadIdx.x;
  int beg = rowptr[d];
  int deg = rowptr[d + 1] - beg;
  if (deg > MAXE - 1) deg = MAXE - 1;  // safety; max in-degree ~30 for this graph
  int ec = deg + 1;                    // + self loop
  if (tid < 8) s_ad[tid] = a_d[d * 8 + tid];
  for (int i = tid; i < deg; i += 256) s_src[i] = csr_src[beg + i];
  if (tid == 0) s_src[deg] = d;
  __syncthreads();
  for (int t = tid; t < ec * 8; t += 256) {
    int i = t >> 3, h = t & 7;
    float e = a_s[s_src[i] * 8 + h] + s_ad[h];
    s_p[t] = (e > 0.f) ? e : 0.2f * e;  // leaky_relu 0.2
  }
  __syncthreads();
  if (tid < 8) {
    float m = -1e30f;
    for (int i = 0; i < ec; ++i) m = fmaxf(m, s_p[i * 8 + tid]);
    float s = 0.f;
    for (int i = 0; i < ec; ++i) {
      float pv = expf(s_p[i * 8 + tid] - m);
      s_p[i * 8 + tid] = pv;
      s += pv;
    }
    s_inv[tid] = 1.f / (s + 1e-16f);
  }
  __syncthreads();
  int h = tid >> 5;
  int f0 = tid << 3;  // 8 channels per thread within the 2048-wide row
  float acc[8] = {0, 0, 0, 0, 0, 0, 0, 0};
  for (int i = 0; i < ec; ++i) {
    int src = s_src[i];
    float pv = s_p[i * 8 + h];
    int4 v = *(const int4*)(xh + (size_t)src * 2048 + f0);
    acc[0] += pv * bfu_lo((unsigned)v.x);
    acc[1] += pv * bfu_hi((unsigned)v.x);
    acc[2] += pv * bfu_lo((unsigned)v.y);
    acc[3] += pv * bfu_hi((unsigned)v.y);
    acc[4] += pv * bfu_lo((unsigned)v.z);
    acc[5] += pv * bfu_hi((unsigned)v.z);
    acc[6] += pv * bfu_lo((unsigned)v.w);
    acc[7] += pv * bfu_hi((unsigned)v.w);
  }
  float inv = s_inv[h];
  float part = 0.f;
  float o[8];
  #pragma unroll
  for (int j = 0; j < 8; ++j) {
    o[j] = acc[j] * inv + b_gat[f0 + j];
    part += o[j];
  }
  int4 ov;
  ov.x = (int)pack2(o[0], o[1]);
  ov.y = (int)pack2(o[2], o[3]);
  ov.z = (int)pack2(o[4], o[5]);
  ov.w = (int)pack2(o[6], o[7]);
  *(int4*)(agg + (size_t)d * 2048 + f0) = ov;
  s_red[tid] = part;
  __syncthreads();
  if (tid < 8) {
    float t2 = 0.f;
    for (int i = 0; i < 32; ++i) t2 += s_red[tid * 32 + i];
    atomicAdd(&pooled[tid], t2);
  }
}

// ---------------- head softmax weights ----------------
__global__ void headw_kernel(const float* __restrict__ pooled, const float* __restrict__ conv_w,
                             const float* __restrict__ conv_b, float* __restrict__ wsoft) {
  if (threadIdx.x == 0 && blockIdx.x == 0) {
    const float inv = 1.0f / (20000.0f * 256.0f);
    float g[8];
    float m = -1e30f;
    for (int h = 0; h < 8; ++h) {
      float v = pooled[h] * inv * conv_w[0] + conv_b[0];
      v = fmaxf(v, 0.f);
      g[h] = v;
      m = fmaxf(m, v);
    }
    float s = 0.f;
    for (int h = 0; h < 8; ++h) { g[h] = expf(g[h] - m); s += g[h]; }
    for (int h = 0; h < 8; ++h) wsoft[h] = g[h] / s;
  }
}

// ---------------- fuse + residual -> Hf (bf16) ----------------
__global__ __launch_bounds__(256) void hf_kernel(const short* __restrict__ agg,
    const float* __restrict__ x, const float* __restrict__ wsoft, short* __restrict__ Hf) {
  int g = blockIdx.x * 256 + threadIdx.x;
  if (g >= 20000 * 32) return;
  int node = g >> 5;
  int c8 = (g & 31) << 3;
  float w[8];
  #pragma unroll
  for (int h = 0; h < 8; ++h) w[h] = wsoft[h];
  float acc[8] = {0, 0, 0, 0, 0, 0, 0, 0};
  #pragma unroll
  for (int h = 0; h < 8; ++h) {
    int4 v = *(const int4*)(agg + (size_t)node * 2048 + h * 256 + c8);
    float wh = w[h];
    acc[0] += wh * bfu_lo((unsigned)v.x);
    acc[1] += wh * bfu_hi((unsigned)v.x);
    acc[2] += wh * bfu_lo((unsigned)v.y);
    acc[3] += wh * bfu_hi((unsigned)v.y);
    acc[4] += wh * bfu_lo((unsigned)v.z);
    acc[5] += wh * bfu_hi((unsigned)v.z);
    acc[6] += wh * bfu_lo((unsigned)v.w);
    acc[7] += wh * bfu_hi((unsigned)v.w);
  }
  const float4* xr = (const float4*)(x + (size_t)node * 256 + c8);
  float4 x0 = xr[0], x1 = xr[1];
  float o[8];
  o[0] = acc[0] + x0.x; o[1] = acc[1] + x0.y; o[2] = acc[2] + x0.z; o[3] = acc[3] + x0.w;
  o[4] = acc[4] + x1.x; o[5] = acc[5] + x1.y; o[6] = acc[6] + x1.z; o[7] = acc[7] + x1.w;
  #pragma unroll
  for (int j = 0; j < 8; ++j) o[j] = fmaxf(o[j], 0.f);
  int4 ov;
  ov.x = (int)pack2(o[0], o[1]);
  ov.y = (int)pack2(o[2], o[3]);
  ov.z = (int)pack2(o[4], o[5]);
  ov.w = (int)pack2(o[6], o[7]);
  *(int4*)(Hf + (size_t)node * 256 + c8) = ov;
}

extern "C" void kernel_launch(void* const* d_in, const int* in_sizes, int n_in,
                              void* d_out, int out_size, void* d_ws, size_t ws_size,
                              hipStream_t stream) {
  (void)in_sizes; (void)n_in; (void)out_size; (void)ws_size;
  const float* x      = (const float*)d_in[0];
  const int*   ei     = (const int*)d_in[1];
  const float* W_gat  = (const float*)d_in[2];
  const float* att_s  = (const float*)d_in[3];
  const float* att_d  = (const float*)d_in[4];
  const float* b_gat  = (const float*)d_in[5];
  const float* conv_w = (const float*)d_in[6];
  const float* conv_b = (const float*)d_in[7];
  const float* W_lin  = (const float*)d_in[8];
  const float* b_lin  = (const float*)d_in[9];
  float* out = (float*)d_out;

  char* p = (char*)d_ws;
  size_t off = 0;
  auto alloc = [&](size_t bytes) -> void* {
    void* r = p + off;
    off = (off + bytes + 255) & ~(size_t)255;
    return r;
  };
  short* x_bf   = (short*)alloc((size_t)20000 * 256 * 2);  // reused as Hf later
  short* wgT    = (short*)alloc((size_t)2048 * 256 * 2);
  short* wlT    = (short*)alloc((size_t)256 * 256 * 2);
  float* ws_s   = (float*)alloc(2048 * 4);
  float* ws_d   = (float*)alloc(2048 * 4);
  float* a_s    = (float*)alloc((size_t)20000 * 8 * 4);
  float* a_d    = (float*)alloc((size_t)20000 * 8 * 4);
  int*   deg    = (int*)alloc(20000 * 4);
  float* pooled = (float*)alloc(8 * 4);
  float* wsoft  = (float*)alloc(8 * 4);
  int*   rowptr = (int*)alloc(20001 * 4);
  int*   cursor = (int*)alloc(20000 * 4);
  int*   csr    = (int*)alloc(200000 * 4);
  short* xh     = (short*)alloc((size_t)20000 * 2048 * 2);
  short* agg    = (short*)alloc((size_t)20000 * 2048 * 2);
  short* Hf     = x_bf;  // x_bf dead after gemm<0>

  hipMemsetAsync(deg, 0, 20000 * 4, stream);
  hipMemsetAsync(pooled, 0, 8 * 4, stream);

  cvt_kernel<<<2500, 256, 0, stream>>>(x, x_bf, 640000);
  transpose_kernel<<<dim3(64, 8), dim3(32, 8), 0, stream>>>(W_gat, wgT, 256, 2048, 2048);
  transpose_kernel<<<dim3(8, 8), dim3(32, 8), 0, stream>>>(W_lin, wlT, 256, 250, 256);
  prepws_kernel<<<8, 256, 0, stream>>>(W_gat, att_s, att_d, ws_s, ws_d);
  asd_kernel<<<625, 256, 0, stream>>>(x, ws_s, ws_d, a_s, a_d);
  gemm_kernel<0><<<157 * 16, 256, 0, stream>>>(x_bf, wgT, 20000, 2048, 256,
                                               xh, nullptr, nullptr, 0);
  hist_kernel<<<782, 256, 0, stream>>>(ei, deg, 200000);
  scan_kernel<<<1, 1024, 0, stream>>>(deg, rowptr, cursor, 20000);
  scatter_kernel<<<782, 256, 0, stream>>>(ei, cursor, csr, 200000);
  agg_kernel<<<20000, 256, 0, stream>>>(xh, a_s, a_d, rowptr, csr, b_gat, agg, pooled);
  headw_kernel<<<1, 64, 0, stream>>>(pooled, conv_w, conv_b, wsoft);
  hf_kernel<<<2500, 256, 0, stream>>>(agg, x, wsoft, Hf);
  gemm_kernel<1><<<157 * 2, 256, 0, stream>>>(Hf, wlT, 20000, 256, 256,
                                              nullptr, out, b_lin, 250);
}

// Round 2
// 328.673 us; speedup vs baseline: 1.4564x; 1.4564x over previous
//
#include <hip/hip_runtime.h>
#include <hip/hip_bf16.h>

// N=20000 nodes, E=200000 edges, H=8, C=256, IN=256, OUT=250, H*C=2048.

typedef __attribute__((ext_vector_type(8))) short short8v;
typedef __attribute__((ext_vector_type(4))) float float4v;

__device__ __forceinline__ unsigned f2bfu(float f) {
  unsigned u = __float_as_uint(f);
  return (u + 0x7fffu + ((u >> 16) & 1u)) >> 16;  // RNE f32 -> bf16
}
__device__ __forceinline__ float bfu_lo(unsigned u) { return __uint_as_float(u << 16); }
__device__ __forceinline__ float bfu_hi(unsigned u) { return __uint_as_float(u & 0xffff0000u); }
__device__ __forceinline__ unsigned pack2(float a, float b) { return f2bfu(a) | (f2bfu(b) << 16); }

__device__ __forceinline__ void ld8(const float* p, float* v) {
  float4 a = ((const float4*)p)[0], b = ((const float4*)p)[1];
  v[0] = a.x; v[1] = a.y; v[2] = a.z; v[3] = a.w;
  v[4] = b.x; v[5] = b.y; v[6] = b.z; v[7] = b.w;
}
__device__ __forceinline__ void st8(float* p, const float* v) {
  ((float4*)p)[0] = make_float4(v[0], v[1], v[2], v[3]);
  ((float4*)p)[1] = make_float4(v[4], v[5], v[6], v[7]);
}

__device__ __forceinline__ void gll16(const void* g, void* l) {
  __builtin_amdgcn_global_load_lds(
      (__attribute__((address_space(1))) void*)const_cast<void*>(g),
      (__attribute__((address_space(3))) void*)(l), 16, 0, 0);
}

// ---------------- small prep kernels ----------------

__global__ void cvt_kernel(const float* __restrict__ in, short* __restrict__ out, int n8) {
  int g = blockIdx.x * 256 + threadIdx.x;
  if (g >= n8) return;
  const float4* p = (const float4*)in + (size_t)g * 2;
  float4 a = p[0], b = p[1];
  int4 o;
  o.x = (int)pack2(a.x, a.y);
  o.y = (int)pack2(a.z, a.w);
  o.z = (int)pack2(b.x, b.y);
  o.w = (int)pack2(b.z, b.w);
  ((int4*)out)[g] = o;
}

// out[c][r] = bf16(in[r][c]); zero-pads columns c in [Cc, Cpad)
__global__ void transpose_kernel(const float* __restrict__ in, short* __restrict__ out,
                                 int R, int Cc, int Cpad) {
  __shared__ float tile[32][33];
  int tx = threadIdx.x, ty = threadIdx.y;
  int c0 = blockIdx.x * 32, r0 = blockIdx.y * 32;
  #pragma unroll
  for (int j = ty; j < 32; j += 8) {
    int r = r0 + j, c = c0 + tx;
    tile[j][tx] = (r < R && c < Cc) ? in[(size_t)r * Cc + c] : 0.f;
  }
  __syncthreads();
  #pragma unroll
  for (int j = ty; j < 32; j += 8) {
    int c = c0 + j, r = r0 + tx;
    if (c < Cpad && r < R) out[(size_t)c * R + r] = (short)f2bfu(tile[tx][j]);
  }
}

// ws_s[k*8+h] = sum_c W[k][h*256+c]*att_src[h][c]; ws_r = plain row-chunk sum (for pooled)
__global__ void prepws_kernel(const float* __restrict__ W, const float* __restrict__ att_s,
                              const float* __restrict__ att_d, float* __restrict__ ws_s,
                              float* __restrict__ ws_d, float* __restrict__ ws_r) {
  int g = blockIdx.x * 256 + threadIdx.x;  // 0..2047
  int k = g >> 3, h = g & 7;
  const float* wr = W + (size_t)k * 2048 + h * 256;
  const float* as = att_s + h * 256;
  const float* ad = att_d + h * 256;
  float s = 0.f, dd = 0.f, r = 0.f;
  for (int c = 0; c < 256; ++c) {
    float wv = wr[c];
    s += wv * as[c];
    dd += wv * ad[c];
    r += wv;
  }
  ws_s[g] = s;
  ws_d[g] = dd;
  ws_r[g] = r;
}

// a_s[n][h], a_d[n][h], rs[n][h] = x[n,:] . ws_*[:,h]  (f32 exact)
__global__ __launch_bounds__(256) void asd_kernel(const float* __restrict__ x,
    const float* __restrict__ ws_s, const float* __restrict__ ws_d,
    const float* __restrict__ ws_r, float* __restrict__ a_s,
    float* __restrict__ a_d, float* __restrict__ rs) {
  __shared__ float ls[2048], ld2[2048], lr[2048];
  int tid = threadIdx.x;
  for (int i = tid; i < 2048; i += 256) { ls[i] = ws_s[i]; ld2[i] = ws_d[i]; lr[i] = ws_r[i]; }
  __syncthreads();
  int node = blockIdx.x * 32 + (tid >> 3);
  int h = tid & 7;
  const float4* xr = (const float4*)(x + (size_t)node * 256);
  float as = 0.f, ad = 0.f, rr = 0.f;
  for (int k4 = 0; k4 < 64; ++k4) {
    float4 v = xr[k4];
    int k8 = k4 * 32 + h;
    as += v.x * ls[k8] + v.y * ls[k8 + 8] + v.z * ls[k8 + 16] + v.w * ls[k8 + 24];
    ad += v.x * ld2[k8] + v.y * ld2[k8 + 8] + v.z * ld2[k8 + 16] + v.w * ld2[k8 + 24];
    rr += v.x * lr[k8] + v.y * lr[k8 + 8] + v.z * lr[k8 + 16] + v.w * lr[k8 + 24];
  }
  a_s[node * 8 + h] = as;
  a_d[node * 8 + h] = ad;
  rs[node * 8 + h] = rr;
}

// ---------------- bf16 MFMA GEMM (128x128 tile, BK=32) ----------------
template <int EPI>
__global__ __launch_bounds__(256, 2) void gemm_kernel(
    const short* __restrict__ A, const short* __restrict__ BT,
    int M, int Npad, int K,
    short* __restrict__ Cb, float* __restrict__ Cf,
    const float* __restrict__ bias, int Nout) {
  __shared__ short lA[128 * 32];
  __shared__ short lB[128 * 32];
  int tid = threadIdx.x;
  int wave = tid >> 6, lane = tid & 63;
  int nt = Npad >> 7;
  int m0 = (blockIdx.x / nt) << 7;
  int n0 = (blockIdx.x % nt) << 7;
  int wm = wave >> 1, wn = wave & 1;

  float4v acc[4][4];
  #pragma unroll
  for (int i = 0; i < 4; ++i)
    #pragma unroll
    for (int j = 0; j < 4; ++j) acc[i][j] = (float4v){0.f, 0.f, 0.f, 0.f};

  int l4 = lane >> 2;
  int lk = (lane & 3) << 3;
  int lr = lane & 15, lq = lane >> 4;

  for (int k0 = 0; k0 < K; k0 += 32) {
    __syncthreads();
    #pragma unroll
    for (int i = 0; i < 2; ++i) {
      int c = wave * 2 + i;
      int ar = m0 + c * 16 + l4;
      if (ar >= M) ar = M - 1;
      gll16(A + (size_t)ar * K + k0 + lk, lA + c * 512);
      int br = n0 + c * 16 + l4;
      gll16(BT + (size_t)br * K + k0 + lk, lB + c * 512);
    }
    __syncthreads();
    short8v af[4], bfv[4];
    #pragma unroll
    for (int i = 0; i < 4; ++i)
      af[i] = *(const short8v*)(lA + (wm * 64 + i * 16 + lr) * 32 + lq * 8);
    #pragma unroll
    for (int j = 0; j < 4; ++j)
      bfv[j] = *(const short8v*)(lB + (wn * 64 + j * 16 + lr) * 32 + lq * 8);
    #pragma unroll
    for (int i = 0; i < 4; ++i)
      #pragma unroll
      for (int j = 0; j < 4; ++j)
        acc[i][j] = __builtin_amdgcn_mfma_f32_16x16x32_bf16(af[i], bfv[j], acc[i][j], 0, 0, 0);
  }

  #pragma unroll
  for (int i = 0; i < 4; ++i) {
    #pragma unroll
    for (int jj = 0; jj < 4; ++jj) {
      int row = m0 + wm * 64 + i * 16 + lq * 4 + jj;
      if (row >= M) continue;
      #pragma unroll
      for (int j = 0; j < 4; ++j) {
        int col = n0 + wn * 64 + j * 16 + lr;
        float v = acc[i][j][jj];
        if (EPI == 0) {
          Cb[(size_t)row * Npad + col] = (short)f2bfu(v);
        } else {
          if (col < Nout) Cf[(size_t)row * Nout + col] = v + bias[col];
        }
      }
    }
  }
}

// ---------------- CSR build ----------------

__global__ void hist_kernel(const int* __restrict__ ei, int* __restrict__ deg, int E) {
  int e = blockIdx.x * 256 + threadIdx.x;
  if (e < E) atomicAdd(&deg[ei[E + e]], 1);
}

// single block, 1024 threads, 20 elems/thread local scan + one 1024-wide scan
__global__ __launch_bounds__(1024) void scan_kernel(const int* __restrict__ deg,
                                                    int* __restrict__ rowptr,
                                                    int* __restrict__ cursor, int n) {
  __shared__ int part[1024];
  int t = threadIdx.x;
  int base = t * 20;
  int loc[20];
  int run = 0;
  #pragma unroll
  for (int j = 0; j < 20; ++j) {
    int idx = base + j;
    int v = (idx < n) ? deg[idx] : 0;
    loc[j] = run;
    run += v;
  }
  part[t] = run;
  __syncthreads();
  for (int off = 1; off < 1024; off <<= 1) {
    int add = (t >= off) ? part[t - off] : 0;
    __syncthreads();
    part[t] += add;
    __syncthreads();
  }
  int off0 = (t > 0) ? part[t - 1] : 0;
  #pragma unroll
  for (int j = 0; j < 20; ++j) {
    int idx = base + j;
    if (idx < n) {
      int v = off0 + loc[j];
      rowptr[idx] = v;
      cursor[idx] = v;
    }
  }
  if (t == 1023) rowptr[n] = part[1023];
}

__global__ void scatter_kernel(const int* __restrict__ ei, int* __restrict__ cursor,
                               int* __restrict__ csr_src, int E) {
  int e = blockIdx.x * 256 + threadIdx.x;
  if (e < E) {
    int pos = atomicAdd(&cursor[ei[E + e]], 1);
    csr_src[pos] = ei[e];
  }
}

// ---------------- per-dst softmax (wave per dst) ----------------
// writes alpha[pos][8] (csr-aligned), aself[d][8], pp[d][8] (pooled partial)
__global__ __launch_bounds__(256) void alpha_kernel(
    const float* __restrict__ a_s, const float* __restrict__ a_d,
    const float* __restrict__ rs, const int* __restrict__ rowptr,
    const int* __restrict__ csr, float* __restrict__ alpha,
    float* __restrict__ aself, float* __restrict__ pp) {
  int d = (blockIdx.x * 256 + threadIdx.x) >> 6;  // grid sized exactly: 20000 waves
  int lane = threadIdx.x & 63;
  int beg = rowptr[d];
  int deg = rowptr[d + 1] - beg;

  float ad[8], es[8], m[8], s[8];
  ld8(a_d + (size_t)d * 8, ad);
  {
    float t[8];
    ld8(a_s + (size_t)d * 8, t);
    #pragma unroll
    for (int h = 0; h < 8; ++h) {
      float e = t[h] + ad[h];
      e = (e > 0.f) ? e : 0.2f * e;
      es[h] = e;
      m[h] = e;
      s[h] = 1.f;  // exp(es - m) = 1
    }
  }

  for (int base = 0; base < deg; base += 64) {
    int i = base + lane;
    bool act = i < deg;
    int src = act ? csr[beg + i] : 0;
    float e[8];
    {
      float t[8];
      ld8(a_s + (size_t)src * 8, t);
      #pragma unroll
      for (int h = 0; h < 8; ++h) {
        float v = t[h] + ad[h];
        v = (v > 0.f) ? v : 0.2f * v;
        e[h] = act ? v : -1e30f;
      }
    }
    float cm[8];
    #pragma unroll
    for (int h = 0; h < 8; ++h) cm[h] = e[h];
    #pragma unroll
    for (int off = 1; off < 64; off <<= 1)
      #pragma unroll
      for (int h = 0; h < 8; ++h) cm[h] = fmaxf(cm[h], __shfl_xor(cm[h], off));
    float nm[8], ex[8];
    #pragma unroll
    for (int h = 0; h < 8; ++h) nm[h] = fmaxf(m[h], cm[h]);
    #pragma unroll
    for (int h = 0; h < 8; ++h) ex[h] = act ? __expf(e[h] - nm[h]) : 0.f;
    #pragma unroll
    for (int off = 1; off < 64; off <<= 1)
      #pragma unroll
      for (int h = 0; h < 8; ++h) ex[h] += __shfl_xor(ex[h], off);
    #pragma unroll
    for (int h = 0; h < 8; ++h) {
      s[h] = s[h] * __expf(m[h] - nm[h]) + ex[h];
      m[h] = nm[h];
    }
  }

  float inv[8], p[8];
  #pragma unroll
  for (int h = 0; h < 8; ++h) inv[h] = 1.f / (s[h] + 1e-16f);
  {
    float rr[8], asf[8];
    ld8(rs + (size_t)d * 8, rr);
    #pragma unroll
    for (int h = 0; h < 8; ++h) {
      float av = __expf(es[h] - m[h]) * inv[h];
      asf[h] = av;
      p[h] = (lane == 0) ? av * rr[h] : 0.f;
    }
    if (lane == 0) st8(aself + (size_t)d * 8, asf);
  }

  for (int base = 0; base < deg; base += 64) {
    int i = base + lane;
    bool act = i < deg;
    int src = act ? csr[beg + i] : 0;
    float al[8];
    {
      float t[8];
      ld8(a_s + (size_t)src * 8, t);
      #pragma unroll
      for (int h = 0; h < 8; ++h) {
        float v = t[h] + ad[h];
        v = (v > 0.f) ? v : 0.2f * v;
        al[h] = act ? __expf(v - m[h]) * inv[h] : 0.f;
      }
    }
    if (act) st8(alpha + (size_t)(beg + i) * 8, al);
    float rr[8];
    ld8(rs + (size_t)src * 8, rr);
    #pragma unroll
    for (int h = 0; h < 8; ++h) p[h] += al[h] * rr[h];
  }
  #pragma unroll
  for (int off = 1; off < 64; off <<= 1)
    #pragma unroll
    for (int h = 0; h < 8; ++h) p[h] += __shfl_xor(p[h], off);
  if (lane == 0) st8(pp + (size_t)d * 8, p);
}

// ---------------- pooled reduction ----------------
__global__ __launch_bounds__(256) void reduce_pp_kernel(const float* __restrict__ pp,
                                                        float* __restrict__ pooled) {
  int tid = threadIdx.x;
  float loc[8] = {0, 0, 0, 0, 0, 0, 0, 0};
  for (int r = blockIdx.x * 256 + tid; r < 20000; r += 80 * 256) {
    float t[8];
    ld8(pp + (size_t)r * 8, t);
    #pragma unroll
    for (int h = 0; h < 8; ++h) loc[h] += t[h];
  }
  #pragma unroll
  for (int off = 1; off < 64; off <<= 1)
    #pragma unroll
    for (int h = 0; h < 8; ++h) loc[h] += __shfl_xor(loc[h], off);
  __shared__ float sred[4][8];
  int wave = tid >> 6, lane = tid & 63;
  if (lane == 0) {
    #pragma unroll
    for (int h = 0; h < 8; ++h) sred[wave][h] = loc[h];
  }
  __syncthreads();
  if (tid < 8) {
    atomicAdd(&pooled[tid], sred[0][tid] + sred[1][tid] + sred[2][tid] + sred[3][tid]);
  }
}

// ---------------- head softmax weights ----------------
__global__ __launch_bounds__(256) void headw_kernel(const float* __restrict__ pooled,
    const float* __restrict__ b_gat, const float* __restrict__ conv_w,
    const float* __restrict__ conv_b, float* __restrict__ wsoft) {
  __shared__ float sb[8];
  int t = threadIdx.x;
  // bsum[h] = sum_c b_gat[h*256+c]; thread t sums 8 elems; 32 threads per head
  float v = 0.f;
  #pragma unroll
  for (int j = 0; j < 8; ++j) v += b_gat[t * 8 + j];
  #pragma unroll
  for (int off = 1; off < 32; off <<= 1) v += __shfl_xor(v, off);
  if ((t & 31) == 0 && t < 256) sb[t >> 5] = v;
  __syncthreads();
  if (t == 0) {
    const float invNC = 1.0f / (20000.0f * 256.0f);
    float g[8];
    float mx = -1e30f;
    #pragma unroll
    for (int h = 0; h < 8; ++h) {
      float pm = (pooled[h] + 20000.0f * sb[h]) * invNC;
      float gv = pm * conv_w[0] + conv_b[0];
      gv = fmaxf(gv, 0.f);
      g[h] = gv;
      mx = fmaxf(mx, gv);
    }
    float ssum = 0.f;
    #pragma unroll
    for (int h = 0; h < 8; ++h) { g[h] = __expf(g[h] - mx); ssum += g[h]; }
    #pragma unroll
    for (int h = 0; h < 8; ++h) wsoft[h] = g[h] / ssum;
  }
}

// fb[c] = sum_h wsoft[h] * b_gat[h*256+c]
__global__ void fb_kernel(const float* __restrict__ b_gat, const float* __restrict__ wsoft,
                          float* __restrict__ fb) {
  int c = threadIdx.x;
  float a = 0.f;
  #pragma unroll
  for (int h = 0; h < 8; ++h) a += wsoft[h] * b_gat[h * 256 + c];
  fb[c] = a;
}

// ---------------- fused gather + head-mix + residual + relu -> Hf (bf16) ----------------
// wave per dst; lane owns channels [lane*4, lane*4+4)
__global__ __launch_bounds__(256) void fuse_kernel(
    const short* __restrict__ xh, const float* __restrict__ x,
    const int* __restrict__ rowptr, const int* __restrict__ csr,
    const float* __restrict__ alpha, const float* __restrict__ aself,
    const float* __restrict__ wsoft, const float* __restrict__ fb,
    short* __restrict__ Hf) {
  int d = (blockIdx.x * 256 + threadIdx.x) >> 6;
  int lane = threadIdx.x & 63;
  float w8[8];
  ld8(wsoft, w8);
  float4 fbv = ((const float4*)fb)[lane];
  float acc0 = fbv.x, acc1 = fbv.y, acc2 = fbv.z, acc3 = fbv.w;
  int beg = rowptr[d];
  int deg = rowptr[d + 1] - beg;
  int nb = deg + 1;  // + self loop (stored separately)

  int src_n;
  float al_n[8];
  if (deg > 0) {
    src_n = csr[beg];
    ld8(alpha + (size_t)beg * 8, al_n);
  } else {
    src_n = d;
    ld8(aself + (size_t)d * 8, al_n);
  }
  for (int i = 0; i < nb; ++i) {
    int src = src_n;
    float q[8];
    #pragma unroll
    for (int h = 0; h < 8; ++h) q[h] = al_n[h] * w8[h];
    int j = i + 1;
    if (j < nb) {
      if (j < deg) {
        src_n = csr[beg + j];
        ld8(alpha + (size_t)(beg + j) * 8, al_n);
      } else {
        src_n = d;
        ld8(aself + (size_t)d * 8, al_n);
      }
    }
    const uint2* row = (const uint2*)(xh + (size_t)src * 2048);
    uint2 v0 = row[0 * 64 + lane];
    uint2 v1 = row[1 * 64 + lane];
    uint2 v2 = row[2 * 64 + lane];
    uint2 v3 = row[3 * 64 + lane];
    uint2 v4 = row[4 * 64 + lane];
    uint2 v5 = row[5 * 64 + lane];
    uint2 v6 = row[6 * 64 + lane];
    uint2 v7 = row[7 * 64 + lane];
    acc0 += q[0] * bfu_lo(v0.x); acc1 += q[0] * bfu_hi(v0.x);
    acc2 += q[0] * bfu_lo(v0.y); acc3 += q[0] * bfu_hi(v0.y);
    acc0 += q[1] * bfu_lo(v1.x); acc1 += q[1] * bfu_hi(v1.x);
    acc2 += q[1] * bfu_lo(v1.y); acc3 += q[1] * bfu_hi(v1.y);
    acc0 += q[2] * bfu_lo(v2.x); acc1 += q[2] * bfu_hi(v2.x);
    acc2 += q[2] * bfu_lo(v2.y); acc3 += q[2] * bfu_hi(v2.y);
    acc0 += q[3] * bfu_lo(v3.x); acc1 += q[3] * bfu_hi(v3.x);
    acc2 += q[3] * bfu_lo(v3.y); acc3 += q[3] * bfu_hi(v3.y);
    acc0 += q[4] * bfu_lo(v4.x); acc1 += q[4] * bfu_hi(v4.x);
    acc2 += q[4] * bfu_lo(v4.y); acc3 += q[4] * bfu_hi(v4.y);
    acc0 += q[5] * bfu_lo(v5.x); acc1 += q[5] * bfu_hi(v5.x);
    acc2 += q[5] * bfu_lo(v5.y); acc3 += q[5] * bfu_hi(v5.y);
    acc0 += q[6] * bfu_lo(v6.x); acc1 += q[6] * bfu_hi(v6.x);
    acc2 += q[6] * bfu_lo(v6.y); acc3 += q[6] * bfu_hi(v6.y);
    acc0 += q[7] * bfu_lo(v7.x); acc1 += q[7] * bfu_hi(v7.x);
    acc2 += q[7] * bfu_lo(v7.y); acc3 += q[7] * bfu_hi(v7.y);
  }
  float4 xr = ((const float4*)(x + (size_t)d * 256))[lane];
  float o0 = fmaxf(acc0 + xr.x, 0.f);
  float o1 = fmaxf(acc1 + xr.y, 0.f);
  float o2 = fmaxf(acc2 + xr.z, 0.f);
  float o3 = fmaxf(acc3 + xr.w, 0.f);
  uint2 ov;
  ov.x = pack2(o0, o1);
  ov.y = pack2(o2, o3);
  *(uint2*)(Hf + (size_t)d * 256 + lane * 4) = ov;
}

extern "C" void kernel_launch(void* const* d_in, const int* in_sizes, int n_in,
                              void* d_out, int out_size, void* d_ws, size_t ws_size,
                              hipStream_t stream) {
  (void)in_sizes; (void)n_in; (void)out_size; (void)ws_size;
  const float* x      = (const float*)d_in[0];
  const int*   ei     = (const int*)d_in[1];
  const float* W_gat  = (const float*)d_in[2];
  const float* att_s  = (const float*)d_in[3];
  const float* att_d  = (const float*)d_in[4];
  const float* b_gat  = (const float*)d_in[5];
  const float* conv_w = (const float*)d_in[6];
  const float* conv_b = (const float*)d_in[7];
  const float* W_lin  = (const float*)d_in[8];
  const float* b_lin  = (const float*)d_in[9];
  float* out = (float*)d_out;

  char* p = (char*)d_ws;
  size_t off = 0;
  auto alloc = [&](size_t bytes) -> void* {
    void* r = p + off;
    off = (off + bytes + 255) & ~(size_t)255;
    return r;
  };
  short* x_bf   = (short*)alloc((size_t)20000 * 256 * 2);  // reused as Hf
  short* wgT    = (short*)alloc((size_t)2048 * 256 * 2);
  short* wlT    = (short*)alloc((size_t)256 * 256 * 2);
  float* ws_s   = (float*)alloc(2048 * 4);
  float* ws_d   = (float*)alloc(2048 * 4);
  float* ws_r   = (float*)alloc(2048 * 4);
  float* a_s    = (float*)alloc((size_t)20000 * 8 * 4);
  float* a_d    = (float*)alloc((size_t)20000 * 8 * 4);
  float* rs     = (float*)alloc((size_t)20000 * 8 * 4);
  int*   deg    = (int*)alloc(20000 * 4);
  float* pooled = (float*)alloc(8 * 4);
  float* wsoft  = (float*)alloc(8 * 4);
  float* fb     = (float*)alloc(256 * 4);
  int*   rowptr = (int*)alloc(20001 * 4);
  int*   cursor = (int*)alloc(20000 * 4);
  int*   csr    = (int*)alloc(200000 * 4);
  float* alpha  = (float*)alloc((size_t)200000 * 8 * 4);
  float* aself  = (float*)alloc((size_t)20000 * 8 * 4);
  float* pp     = (float*)alloc((size_t)20000 * 8 * 4);
  short* xh     = (short*)alloc((size_t)20000 * 2048 * 2);
  short* Hf     = x_bf;  // x_bf dead after gemm<0>

  hipMemsetAsync(deg, 0, 20000 * 4, stream);
  hipMemsetAsync(pooled, 0, 8 * 4, stream);

  cvt_kernel<<<2500, 256, 0, stream>>>(x, x_bf, 640000);
  transpose_kernel<<<dim3(64, 8), dim3(32, 8), 0, stream>>>(W_gat, wgT, 256, 2048, 2048);
  transpose_kernel<<<dim3(8, 8), dim3(32, 8), 0, stream>>>(W_lin, wlT, 256, 250, 256);
  prepws_kernel<<<8, 256, 0, stream>>>(W_gat, att_s, att_d, ws_s, ws_d, ws_r);
  asd_kernel<<<625, 256, 0, stream>>>(x, ws_s, ws_d, ws_r, a_s, a_d, rs);
  hist_kernel<<<782, 256, 0, stream>>>(ei, deg, 200000);
  scan_kernel<<<1, 1024, 0, stream>>>(deg, rowptr, cursor, 20000);
  scatter_kernel<<<782, 256, 0, stream>>>(ei, cursor, csr, 200000);
  alpha_kernel<<<5000, 256, 0, stream>>>(a_s, a_d, rs, rowptr, csr, alpha, aself, pp);
  reduce_pp_kernel<<<80, 256, 0, stream>>>(pp, pooled);
  headw_kernel<<<1, 256, 0, stream>>>(pooled, b_gat, conv_w, conv_b, wsoft);
  fb_kernel<<<1, 256, 0, stream>>>(b_gat, wsoft, fb);
  gemm_kernel<0><<<157 * 16, 256, 0, stream>>>(x_bf, wgT, 20000, 2048, 256,
                                               xh, nullptr, nullptr, 0);
  fuse_kernel<<<5000, 256, 0, stream>>>(xh, x, rowptr, csr, alpha, aself, wsoft, fb, Hf);
  gemm_kernel<1><<<157 * 2, 256, 0, stream>>>(Hf, wlT, 20000, 256, 256,
                                              nullptr, out, b_lin, 250);
}

// Round 3
// 261.333 us; speedup vs baseline: 1.8317x; 1.2577x over previous
//
#include <hip/hip_runtime.h>
#include <hip/hip_bf16.h>

// N=20000 nodes, E=200000 edges, H=8, C=256, IN=256, OUT=250, H*C=2048.
// R3: sum-swap — aggregate x rows (512B) per edge instead of xh rows (4KB);
//     xh/GEMM1/fuse deleted; one GEMM u@Wmix with fused +fb+x relu epilogue.

typedef __attribute__((ext_vector_type(8))) short short8v;
typedef __attribute__((ext_vector_type(4))) float float4v;

__device__ __forceinline__ unsigned f2bfu(float f) {
  unsigned u = __float_as_uint(f);
  return (u + 0x7fffu + ((u >> 16) & 1u)) >> 16;  // RNE f32 -> bf16
}
__device__ __forceinline__ float bfu_lo(unsigned u) { return __uint_as_float(u << 16); }
__device__ __forceinline__ float bfu_hi(unsigned u) { return __uint_as_float(u & 0xffff0000u); }
__device__ __forceinline__ unsigned pack2(float a, float b) { return f2bfu(a) | (f2bfu(b) << 16); }

__device__ __forceinline__ void ld8(const float* p, float* v) {
  float4 a = ((const float4*)p)[0], b = ((const float4*)p)[1];
  v[0] = a.x; v[1] = a.y; v[2] = a.z; v[3] = a.w;
  v[4] = b.x; v[5] = b.y; v[6] = b.z; v[7] = b.w;
}
__device__ __forceinline__ void st8(float* p, const float* v) {
  ((float4*)p)[0] = make_float4(v[0], v[1], v[2], v[3]);
  ((float4*)p)[1] = make_float4(v[4], v[5], v[6], v[7]);
}

__device__ __forceinline__ void gll16(const void* g, void* l) {
  __builtin_amdgcn_global_load_lds(
      (__attribute__((address_space(1))) void*)const_cast<void*>(g),
      (__attribute__((address_space(3))) void*)(l), 16, 0, 0);
}

// ---------------- small prep kernels ----------------

__global__ void cvt_kernel(const float* __restrict__ in, short* __restrict__ out, int n8) {
  int g = blockIdx.x * 256 + threadIdx.x;
  if (g >= n8) return;
  const float4* p = (const float4*)in + (size_t)g * 2;
  float4 a = p[0], b = p[1];
  int4 o;
  o.x = (int)pack2(a.x, a.y);
  o.y = (int)pack2(a.z, a.w);
  o.z = (int)pack2(b.x, b.y);
  o.w = (int)pack2(b.z, b.w);
  ((int4*)out)[g] = o;
}

// out[c][r] = bf16(in[r][c]); zero-pads columns c in [Cc, Cpad)
__global__ void transpose_kernel(const float* __restrict__ in, short* __restrict__ out,
                                 int R, int Cc, int Cpad) {
  __shared__ float tile[32][33];
  int tx = threadIdx.x, ty = threadIdx.y;
  int c0 = blockIdx.x * 32, r0 = blockIdx.y * 32;
  #pragma unroll
  for (int j = ty; j < 32; j += 8) {
    int r = r0 + j, c = c0 + tx;
    tile[j][tx] = (r < R && c < Cc) ? in[(size_t)r * Cc + c] : 0.f;
  }
  __syncthreads();
  #pragma unroll
  for (int j = ty; j < 32; j += 8) {
    int c = c0 + j, r = r0 + tx;
    if (c < Cpad && r < R) out[(size_t)c * R + r] = (short)f2bfu(tile[tx][j]);
  }
}

// wmixT[c][h*256+k] = bf16(W_gat[k][h*256+c])  (per-head 256x256 block transpose)
__global__ void wmix_kernel(const float* __restrict__ W, short* __restrict__ out) {
  __shared__ float tile[32][33];
  int tx = threadIdx.x, ty = threadIdx.y;
  int h = blockIdx.z;
  int c0 = blockIdx.x * 32, k0 = blockIdx.y * 32;
  #pragma unroll
  for (int j = ty; j < 32; j += 8)
    tile[j][tx] = W[(size_t)(k0 + j) * 2048 + h * 256 + c0 + tx];
  __syncthreads();
  #pragma unroll
  for (int j = ty; j < 32; j += 8)
    out[(size_t)(c0 + j) * 2048 + h * 256 + k0 + tx] = (short)f2bfu(tile[tx][j]);
}

// ws_s[k*8+h] = sum_c W[k][h*256+c]*att_src[h][c]; ws_r = plain row-chunk sum
__global__ void prepws_kernel(const float* __restrict__ W, const float* __restrict__ att_s,
                              const float* __restrict__ att_d, float* __restrict__ ws_s,
                              float* __restrict__ ws_d, float* __restrict__ ws_r) {
  int g = blockIdx.x * 256 + threadIdx.x;  // 0..2047
  int k = g >> 3, h = g & 7;
  const float* wr = W + (size_t)k * 2048 + h * 256;
  const float* as = att_s + h * 256;
  const float* ad = att_d + h * 256;
  float s = 0.f, dd = 0.f, r = 0.f;
  for (int c = 0; c < 256; ++c) {
    float wv = wr[c];
    s += wv * as[c];
    dd += wv * ad[c];
    r += wv;
  }
  ws_s[g] = s;
  ws_d[g] = dd;
  ws_r[g] = r;
}

// a_s[n][h], a_d[n][h], rs[n][h] = x[n,:] . ws_*[:,h]  (f32 exact)
__global__ __launch_bounds__(256) void asd_kernel(const float* __restrict__ x,
    const float* __restrict__ ws_s, const float* __restrict__ ws_d,
    const float* __restrict__ ws_r, float* __restrict__ a_s,
    float* __restrict__ a_d, float* __restrict__ rs) {
  __shared__ float ls[2048], ld2[2048], lr[2048];
  int tid = threadIdx.x;
  for (int i = tid; i < 2048; i += 256) { ls[i] = ws_s[i]; ld2[i] = ws_d[i]; lr[i] = ws_r[i]; }
  __syncthreads();
  int node = blockIdx.x * 32 + (tid >> 3);
  int h = tid & 7;
  const float4* xr = (const float4*)(x + (size_t)node * 256);
  float as = 0.f, ad = 0.f, rr = 0.f;
  for (int k4 = 0; k4 < 64; ++k4) {
    float4 v = xr[k4];
    int k8 = k4 * 32 + h;
    as += v.x * ls[k8] + v.y * ls[k8 + 8] + v.z * ls[k8 + 16] + v.w * ls[k8 + 24];
    ad += v.x * ld2[k8] + v.y * ld2[k8 + 8] + v.z * ld2[k8 + 16] + v.w * ld2[k8 + 24];
    rr += v.x * lr[k8] + v.y * lr[k8 + 8] + v.z * lr[k8 + 16] + v.w * lr[k8 + 24];
  }
  a_s[node * 8 + h] = as;
  a_d[node * 8 + h] = ad;
  rs[node * 8 + h] = rr;
}

// ---------------- bf16 MFMA GEMM (128x128 tile, BK=32) ----------------
// EPI=1: f32 store + bias, col<Nout.  EPI=2: bf16 store of relu(acc+bias+xres).
template <int EPI>
__global__ __launch_bounds__(256, 2) void gemm_kernel(
    const short* __restrict__ A, const short* __restrict__ BT,
    int M, int Npad, int K,
    short* __restrict__ Cb, float* __restrict__ Cf,
    const float* __restrict__ bias, const float* __restrict__ xres, int Nout) {
  __shared__ short lA[128 * 32];
  __shared__ short lB[128 * 32];
  int tid = threadIdx.x;
  int wave = tid >> 6, lane = tid & 63;
  int nt = Npad >> 7;
  int m0 = (blockIdx.x / nt) << 7;
  int n0 = (blockIdx.x % nt) << 7;
  int wm = wave >> 1, wn = wave & 1;

  float4v acc[4][4];
  #pragma unroll
  for (int i = 0; i < 4; ++i)
    #pragma unroll
    for (int j = 0; j < 4; ++j) acc[i][j] = (float4v){0.f, 0.f, 0.f, 0.f};

  int l4 = lane >> 2;
  int lk = (lane & 3) << 3;
  int lr = lane & 15, lq = lane >> 4;

  for (int k0 = 0; k0 < K; k0 += 32) {
    __syncthreads();
    #pragma unroll
    for (int i = 0; i < 2; ++i) {
      int c = wave * 2 + i;
      int ar = m0 + c * 16 + l4;
      if (ar >= M) ar = M - 1;
      gll16(A + (size_t)ar * K + k0 + lk, lA + c * 512);
      int br = n0 + c * 16 + l4;
      gll16(BT + (size_t)br * K + k0 + lk, lB + c * 512);
    }
    __syncthreads();
    short8v af[4], bfv[4];
    #pragma unroll
    for (int i = 0; i < 4; ++i)
      af[i] = *(const short8v*)(lA + (wm * 64 + i * 16 + lr) * 32 + lq * 8);
    #pragma unroll
    for (int j = 0; j < 4; ++j)
      bfv[j] = *(const short8v*)(lB + (wn * 64 + j * 16 + lr) * 32 + lq * 8);
    #pragma unroll
    for (int i = 0; i < 4; ++i)
      #pragma unroll
      for (int j = 0; j < 4; ++j)
        acc[i][j] = __builtin_amdgcn_mfma_f32_16x16x32_bf16(af[i], bfv[j], acc[i][j], 0, 0, 0);
  }

  #pragma unroll
  for (int i = 0; i < 4; ++i) {
    #pragma unroll
    for (int jj = 0; jj < 4; ++jj) {
      int row = m0 + wm * 64 + i * 16 + lq * 4 + jj;
      if (row >= M) continue;
      #pragma unroll
      for (int j = 0; j < 4; ++j) {
        int col = n0 + wn * 64 + j * 16 + lr;
        float v = acc[i][j][jj];
        if (EPI == 1) {
          if (col < Nout) Cf[(size_t)row * Nout + col] = v + bias[col];
        } else {
          float o = v + bias[col] + xres[(size_t)row * 256 + col];
          Cb[(size_t)row * Npad + col] = (short)f2bfu(fmaxf(o, 0.f));
        }
      }
    }
  }
}

// ---------------- CSR build ----------------

__global__ void hist_kernel(const int* __restrict__ ei, int* __restrict__ deg, int E) {
  int e = blockIdx.x * 256 + threadIdx.x;
  if (e < E) atomicAdd(&deg[ei[E + e]], 1);
}

// single block, 1024 threads, 20 elems/thread local scan + one 1024-wide scan
__global__ __launch_bounds__(1024) void scan_kernel(const int* __restrict__ deg,
                                                    int* __restrict__ rowptr,
                                                    int* __restrict__ cursor, int n) {
  __shared__ int part[1024];
  int t = threadIdx.x;
  int base = t * 20;
  int loc[20];
  int run = 0;
  #pragma unroll
  for (int j = 0; j < 20; ++j) {
    int idx = base + j;
    int v = (idx < n) ? deg[idx] : 0;
    loc[j] = run;
    run += v;
  }
  part[t] = run;
  __syncthreads();
  for (int off = 1; off < 1024; off <<= 1) {
    int add = (t >= off) ? part[t - off] : 0;
    __syncthreads();
    part[t] += add;
    __syncthreads();
  }
  int off0 = (t > 0) ? part[t - 1] : 0;
  #pragma unroll
  for (int j = 0; j < 20; ++j) {
    int idx = base + j;
    if (idx < n) {
      int v = off0 + loc[j];
      rowptr[idx] = v;
      cursor[idx] = v;
    }
  }
  if (t == 1023) rowptr[n] = part[1023];
}

__global__ void scatter_kernel(const int* __restrict__ ei, int* __restrict__ cursor,
                               int* __restrict__ csr_src, int E) {
  int e = blockIdx.x * 256 + threadIdx.x;
  if (e < E) {
    int pos = atomicAdd(&cursor[ei[E + e]], 1);
    csr_src[pos] = ei[e];
  }
}

// ---------------- per-dst softmax (wave per dst) ----------------
__global__ __launch_bounds__(256) void alpha_kernel(
    const float* __restrict__ a_s, const float* __restrict__ a_d,
    const float* __restrict__ rs, const int* __restrict__ rowptr,
    const int* __restrict__ csr, float* __restrict__ alpha,
    float* __restrict__ aself, float* __restrict__ pp) {
  int d = (blockIdx.x * 256 + threadIdx.x) >> 6;
  int lane = threadIdx.x & 63;
  int beg = rowptr[d];
  int deg = rowptr[d + 1] - beg;

  float ad[8], es[8], m[8], s[8];
  ld8(a_d + (size_t)d * 8, ad);
  {
    float t[8];
    ld8(a_s + (size_t)d * 8, t);
    #pragma unroll
    for (int h = 0; h < 8; ++h) {
      float e = t[h] + ad[h];
      e = (e > 0.f) ? e : 0.2f * e;
      es[h] = e;
      m[h] = e;
      s[h] = 1.f;
    }
  }

  for (int base = 0; base < deg; base += 64) {
    int i = base + lane;
    bool act = i < deg;
    int src = act ? csr[beg + i] : 0;
    float e[8];
    {
      float t[8];
      ld8(a_s + (size_t)src * 8, t);
      #pragma unroll
      for (int h = 0; h < 8; ++h) {
        float v = t[h] + ad[h];
        v = (v > 0.f) ? v : 0.2f * v;
        e[h] = act ? v : -1e30f;
      }
    }
    float cm[8];
    #pragma unroll
    for (int h = 0; h < 8; ++h) cm[h] = e[h];
    #pragma unroll
    for (int off = 1; off < 64; off <<= 1)
      #pragma unroll
      for (int h = 0; h < 8; ++h) cm[h] = fmaxf(cm[h], __shfl_xor(cm[h], off));
    float nm[8], ex[8];
    #pragma unroll
    for (int h = 0; h < 8; ++h) nm[h] = fmaxf(m[h], cm[h]);
    #pragma unroll
    for (int h = 0; h < 8; ++h) ex[h] = act ? __expf(e[h] - nm[h]) : 0.f;
    #pragma unroll
    for (int off = 1; off < 64; off <<= 1)
      #pragma unroll
      for (int h = 0; h < 8; ++h) ex[h] += __shfl_xor(ex[h], off);
    #pragma unroll
    for (int h = 0; h < 8; ++h) {
      s[h] = s[h] * __expf(m[h] - nm[h]) + ex[h];
      m[h] = nm[h];
    }
  }

  float inv[8], p[8];
  #pragma unroll
  for (int h = 0; h < 8; ++h) inv[h] = 1.f / (s[h] + 1e-16f);
  {
    float rr[8], asf[8];
    ld8(rs + (size_t)d * 8, rr);
    #pragma unroll
    for (int h = 0; h < 8; ++h) {
      float av = __expf(es[h] - m[h]) * inv[h];
      asf[h] = av;
      p[h] = (lane == 0) ? av * rr[h] : 0.f;
    }
    if (lane == 0) st8(aself + (size_t)d * 8, asf);
  }

  for (int base = 0; base < deg; base += 64) {
    int i = base + lane;
    bool act = i < deg;
    int src = act ? csr[beg + i] : 0;
    float al[8];
    {
      float t[8];
      ld8(a_s + (size_t)src * 8, t);
      #pragma unroll
      for (int h = 0; h < 8; ++h) {
        float v = t[h] + ad[h];
        v = (v > 0.f) ? v : 0.2f * v;
        al[h] = act ? __expf(v - m[h]) * inv[h] : 0.f;
      }
    }
    if (act) st8(alpha + (size_t)(beg + i) * 8, al);
    float rr[8];
    ld8(rs + (size_t)src * 8, rr);
    #pragma unroll
    for (int h = 0; h < 8; ++h) p[h] += al[h] * rr[h];
  }
  #pragma unroll
  for (int off = 1; off < 64; off <<= 1)
    #pragma unroll
    for (int h = 0; h < 8; ++h) p[h] += __shfl_xor(p[h], off);
  if (lane == 0) st8(pp + (size_t)d * 8, p);
}

// ---------------- pooled reduction ----------------
__global__ __launch_bounds__(256) void reduce_pp_kernel(const float* __restrict__ pp,
                                                        float* __restrict__ pooled) {
  int tid = threadIdx.x;
  float loc[8] = {0, 0, 0, 0, 0, 0, 0, 0};
  for (int r = blockIdx.x * 256 + tid; r < 20000; r += 80 * 256) {
    float t[8];
    ld8(pp + (size_t)r * 8, t);
    #pragma unroll
    for (int h = 0; h < 8; ++h) loc[h] += t[h];
  }
  #pragma unroll
  for (int off = 1; off < 64; off <<= 1)
    #pragma unroll
    for (int h = 0; h < 8; ++h) loc[h] += __shfl_xor(loc[h], off);
  __shared__ float sred[4][8];
  int wave = tid >> 6, lane = tid & 63;
  if (lane == 0) {
    #pragma unroll
    for (int h = 0; h < 8; ++h) sred[wave][h] = loc[h];
  }
  __syncthreads();
  if (tid < 8) {
    atomicAdd(&pooled[tid], sred[0][tid] + sred[1][tid] + sred[2][tid] + sred[3][tid]);
  }
}

// ---------------- head softmax weights ----------------
__global__ __launch_bounds__(256) void headw_kernel(const float* __restrict__ pooled,
    const float* __restrict__ b_gat, const float* __restrict__ conv_w,
    const float* __restrict__ conv_b, float* __restrict__ wsoft) {
  __shared__ float sb[8];
  int t = threadIdx.x;
  float v = 0.f;
  #pragma unroll
  for (int j = 0; j < 8; ++j) v += b_gat[t * 8 + j];
  #pragma unroll
  for (int off = 1; off < 32; off <<= 1) v += __shfl_xor(v, off);
  if ((t & 31) == 0 && t < 256) sb[t >> 5] = v;
  __syncthreads();
  if (t == 0) {
    const float invNC = 1.0f / (20000.0f * 256.0f);
    float g[8];
    float mx = -1e30f;
    #pragma unroll
    for (int h = 0; h < 8; ++h) {
      float pm = (pooled[h] + 20000.0f * sb[h]) * invNC;
      float gv = pm * conv_w[0] + conv_b[0];
      gv = fmaxf(gv, 0.f);
      g[h] = gv;
      mx = fmaxf(mx, gv);
    }
    float ssum = 0.f;
    #pragma unroll
    for (int h = 0; h < 8; ++h) { g[h] = __expf(g[h] - mx); ssum += g[h]; }
    #pragma unroll
    for (int h = 0; h < 8; ++h) wsoft[h] = g[h] / ssum;
  }
}

// fb[c] = sum_h wsoft[h] * b_gat[h*256+c]
__global__ void fb_kernel(const float* __restrict__ b_gat, const float* __restrict__ wsoft,
                          float* __restrict__ fb) {
  int c = threadIdx.x;
  float a = 0.f;
  #pragma unroll
  for (int h = 0; h < 8; ++h) a += wsoft[h] * b_gat[h * 256 + c];
  fb[c] = a;
}

// ---------------- z-aggregate with head fold: u[d][h*256+k] = w_h * sum_e alpha_eh x[src][k]
// wave per dst; lane owns k = lane*4 .. lane*4+3
__global__ __launch_bounds__(256) void zmix_kernel(
    const short* __restrict__ x_bf, const int* __restrict__ rowptr,
    const int* __restrict__ csr, const float* __restrict__ alpha,
    const float* __restrict__ aself, const float* __restrict__ wsoft,
    short* __restrict__ u) {
  int d = (blockIdx.x * 256 + threadIdx.x) >> 6;
  int lane = threadIdx.x & 63;
  int beg = rowptr[d];
  int deg = rowptr[d + 1] - beg;
  int nb = deg + 1;

  float acc[8][4];
  #pragma unroll
  for (int h = 0; h < 8; ++h)
    #pragma unroll
    for (int j = 0; j < 4; ++j) acc[h][j] = 0.f;

  int src_c;
  float al_c[8];
  if (deg > 0) {
    src_c = csr[beg];
    ld8(alpha + (size_t)beg * 8, al_c);
  } else {
    src_c = d;
    ld8(aself + (size_t)d * 8, al_c);
  }
  uint2 v_c = *(const uint2*)(x_bf + (size_t)src_c * 256 + lane * 4);

  for (int i = 0; i < nb; ++i) {
    int j = i + 1;
    float al_n[8];
    uint2 v_n;
    bool has = j < nb;
    if (has) {
      int src_n;
      if (j < deg) {
        src_n = csr[beg + j];
        ld8(alpha + (size_t)(beg + j) * 8, al_n);
      } else {
        src_n = d;
        ld8(aself + (size_t)d * 8, al_n);
      }
      v_n = *(const uint2*)(x_bf + (size_t)src_n * 256 + lane * 4);
    }
    float xv0 = bfu_lo(v_c.x), xv1 = bfu_hi(v_c.x);
    float xv2 = bfu_lo(v_c.y), xv3 = bfu_hi(v_c.y);
    #pragma unroll
    for (int h = 0; h < 8; ++h) {
      float a = al_c[h];
      acc[h][0] += a * xv0;
      acc[h][1] += a * xv1;
      acc[h][2] += a * xv2;
      acc[h][3] += a * xv3;
    }
    if (has) {
      #pragma unroll
      for (int h = 0; h < 8; ++h) al_c[h] = al_n[h];
      v_c = v_n;
    }
  }

  float w8[8];
  ld8(wsoft, w8);
  #pragma unroll
  for (int h = 0; h < 8; ++h) {
    uint2 ov;
    ov.x = pack2(acc[h][0] * w8[h], acc[h][1] * w8[h]);
    ov.y = pack2(acc[h][2] * w8[h], acc[h][3] * w8[h]);
    *(uint2*)(u + (size_t)d * 2048 + h * 256 + lane * 4) = ov;
  }
}

extern "C" void kernel_launch(void* const* d_in, const int* in_sizes, int n_in,
                              void* d_out, int out_size, void* d_ws, size_t ws_size,
                              hipStream_t stream) {
  (void)in_sizes; (void)n_in; (void)out_size; (void)ws_size;
  const float* x      = (const float*)d_in[0];
  const int*   ei     = (const int*)d_in[1];
  const float* W_gat  = (const float*)d_in[2];
  const float* att_s  = (const float*)d_in[3];
  const float* att_d  = (const float*)d_in[4];
  const float* b_gat  = (const float*)d_in[5];
  const float* conv_w = (const float*)d_in[6];
  const float* conv_b = (const float*)d_in[7];
  const float* W_lin  = (const float*)d_in[8];
  const float* b_lin  = (const float*)d_in[9];
  float* out = (float*)d_out;

  char* p = (char*)d_ws;
  size_t off = 0;
  auto alloc = [&](size_t bytes) -> void* {
    void* r = p + off;
    off = (off + bytes + 255) & ~(size_t)255;
    return r;
  };
  short* x_bf   = (short*)alloc((size_t)20000 * 256 * 2);  // reused as Hf after zmix
  short* wmixT  = (short*)alloc((size_t)256 * 2048 * 2);
  short* wlT    = (short*)alloc((size_t)256 * 256 * 2);
  float* ws_s   = (float*)alloc(2048 * 4);
  float* ws_d   = (float*)alloc(2048 * 4);
  float* ws_r   = (float*)alloc(2048 * 4);
  float* a_s    = (float*)alloc((size_t)20000 * 8 * 4);
  float* a_d    = (float*)alloc((size_t)20000 * 8 * 4);
  float* rs     = (float*)alloc((size_t)20000 * 8 * 4);
  int*   deg    = (int*)alloc(20000 * 4);
  float* pooled = (float*)alloc(8 * 4);
  float* wsoft  = (float*)alloc(8 * 4);
  float* fb     = (float*)alloc(256 * 4);
  int*   rowptr = (int*)alloc(20001 * 4);
  int*   cursor = (int*)alloc(20000 * 4);
  int*   csr    = (int*)alloc(200000 * 4);
  float* alpha  = (float*)alloc((size_t)200000 * 8 * 4);
  float* aself  = (float*)alloc((size_t)20000 * 8 * 4);
  float* pp     = (float*)alloc((size_t)20000 * 8 * 4);
  short* u      = (short*)alloc((size_t)20000 * 2048 * 2);
  short* Hf     = x_bf;  // x_bf dead after zmix; Hf written by gemm<2>

  hipMemsetAsync(deg, 0, 20000 * 4, stream);
  hipMemsetAsync(pooled, 0, 8 * 4, stream);

  cvt_kernel<<<2500, 256, 0, stream>>>(x, x_bf, 640000);
  wmix_kernel<<<dim3(8, 8, 8), dim3(32, 8), 0, stream>>>(W_gat, wmixT);
  transpose_kernel<<<dim3(8, 8), dim3(32, 8), 0, stream>>>(W_lin, wlT, 256, 250, 256);
  prepws_kernel<<<8, 256, 0, stream>>>(W_gat, att_s, att_d, ws_s, ws_d, ws_r);
  asd_kernel<<<625, 256, 0, stream>>>(x, ws_s, ws_d, ws_r, a_s, a_d, rs);
  hist_kernel<<<782, 256, 0, stream>>>(ei, deg, 200000);
  scan_kernel<<<1, 1024, 0, stream>>>(deg, rowptr, cursor, 20000);
  scatter_kernel<<<782, 256, 0, stream>>>(ei, cursor, csr, 200000);
  alpha_kernel<<<5000, 256, 0, stream>>>(a_s, a_d, rs, rowptr, csr, alpha, aself, pp);
  reduce_pp_kernel<<<80, 256, 0, stream>>>(pp, pooled);
  headw_kernel<<<1, 256, 0, stream>>>(pooled, b_gat, conv_w, conv_b, wsoft);
  fb_kernel<<<1, 256, 0, stream>>>(b_gat, wsoft, fb);
  zmix_kernel<<<5000, 256, 0, stream>>>(x_bf, rowptr, csr, alpha, aself, wsoft, u);
  // Hf = relu(u @ Wmix + fb + x)  [20000x256 bf16]
  gemm_kernel<2><<<157 * 2, 256, 0, stream>>>(u, wmixT, 20000, 256, 2048,
                                              Hf, nullptr, fb, x, 256);
  // out = Hf @ W_lin + b_lin  [20000x250 f32]
  gemm_kernel<1><<<157 * 2, 256, 0, stream>>>(Hf, wlT, 20000, 256, 256,
                                              nullptr, out, b_lin, nullptr, 250);
}